// Round 1
// baseline (585.028 us; speedup 1.0000x reference)
//
#include <hip/hip_runtime.h>
#include <cstdint>

// Problem geometry (fixed by setup_inputs):
//   x: (8,256,128,128) f32   -> out: same
//   Binary net: all convs are XNOR-popcount over bitpacked +/-1 tensors.
// Bit convention: bit = 1  <=>  value < 0  (i.e. binarize -> -1)
// dot over one tap = 256 - 2*popc(a ^ w); zero-padded taps masked out.
//
// R1 change vs 613us baseline: weights are read via wave-uniform addresses
// (forced with readfirstlane) directly from global memory -> compiler emits
// scalar s_load into SGPRs (L2-resident, dual-issue with VALU), removing the
// LDS staging, both __syncthreads, and all LDS-pipe traffic in layer1/layer2.

#define HWD 128
#define NB  8

// ---------------- pack x -> xb (1 word per 32 channels) --------------------
__global__ __launch_bounds__(256) void pack_x(const float* __restrict__ x,
                                              uint32_t* __restrict__ xb) {
  int id = blockIdx.x * 256 + threadIdx.x;        // 0 .. 1048575
  int w  = id & 127;
  int wd = (id >> 7) & 7;
  int h  = (id >> 10) & 127;
  int n  = id >> 17;
  const float* src = x + ((n * 256 + wd * 32) << 14) + (h << 7) + w;
  uint32_t bits = 0;
#pragma unroll
  for (int i = 0; i < 32; ++i) {
    float v = src[i << 14];
    bits |= (v < 0.0f ? 1u : 0u) << i;
  }
  xb[(((((n << 7) + h) << 7) + w) << 3) + wd] = bits;
}

// ---------------- pack weights (binarized) + concat bias -------------------
// wl1: [4 branches][64 oc][5 taps][8 words]   = 10240 words
// wl2: [256 oc][9 taps][8 words]              = 18432 words
// bcat: [256] f32 (b1|b2|b3|b4)
__global__ __launch_bounds__(256) void pack_w(
    const float* __restrict__ w1, const float* __restrict__ w2,
    const float* __restrict__ w3, const float* __restrict__ w4,
    const float* __restrict__ wc,
    const float* __restrict__ b1, const float* __restrict__ b2,
    const float* __restrict__ b3, const float* __restrict__ b4,
    uint32_t* __restrict__ wl1, uint32_t* __restrict__ wl2,
    float* __restrict__ bcat) {
  int id = blockIdx.x * 256 + threadIdx.x;        // 0 .. 28927
  if (id < 10240) {
    int wd  = id & 7;
    int tap = (id >> 3) % 5;
    int oc  = (id / 40) & 63;
    int br  = id / 2560;
    const float* w = (br == 0) ? w1 : (br == 1) ? w2 : (br == 2) ? w3 : w4;
    uint32_t bits = 0;
#pragma unroll
    for (int i = 0; i < 32; ++i) {
      float v = w[(oc * 256 + wd * 32 + i) * 5 + tap];
      bits |= (v < 0.0f ? 1u : 0u) << i;
    }
    wl1[id] = bits;
  } else if (id < 28672) {
    int id2 = id - 10240;
    int wd  = id2 & 7;
    int tap = (id2 >> 3) % 9;
    int oc  = id2 / 72;
    uint32_t bits = 0;
#pragma unroll
    for (int i = 0; i < 32; ++i) {
      float v = wc[(oc * 256 + wd * 32 + i) * 9 + tap];
      bits |= (v < 0.0f ? 1u : 0u) << i;
    }
    wl2[id2] = bits;
  } else if (id < 28928) {
    int c = id - 28672;
    float v = (c < 64) ? b1[c] : (c < 128) ? b2[c - 64]
              : (c < 192) ? b3[c - 128] : b4[c - 192];
    bcat[c] = v;
  }
}

// ---------------- layer 1: 4 binary branches + bias + PReLU + binarize ----
__global__ __launch_bounds__(256) void layer1(
    const uint32_t* __restrict__ xb, uint32_t* __restrict__ yb,
    const uint32_t* __restrict__ wl1, const float* __restrict__ bcat,
    const float* __restrict__ a1p) {
  const float a1 = a1p[0];
  int p = blockIdx.x * 256 + threadIdx.x;
  int w = p & 127, h = (p >> 7) & 127, n = p >> 14;

  uint32_t outw[8];
#pragma unroll
  for (int br = 0; br < 4; ++br) {
    uint4 ia[5], ib[5];
    int msk[5];
    int nval = 0;
#pragma unroll
    for (int tap = 0; tap < 5; ++tap) {
      int dh = 0, dw = 0;
      if (br == 0) dw = tap - 2;
      else if (br == 1) dw = 2 * tap - 4;
      else if (br == 2) dh = tap - 2;
      else dh = 2 * tap - 4;
      int hh = h + dh, ww = w + dw;
      bool v = (hh >= 0) && (hh < HWD) && (ww >= 0) && (ww < HWD);
      msk[tap] = v ? -1 : 0;
      nval += v ? 1 : 0;
      int hc = min(max(hh, 0), HWD - 1), wc2 = min(max(ww, 0), HWD - 1);
      const uint4* src = (const uint4*)(xb + (((((n << 7) + hc) << 7) + wc2) << 3));
      ia[tap] = src[0];
      ib[tap] = src[1];
    }
    int basev = 256 * nval;
    uint32_t bits[2];
#pragma unroll
    for (int half = 0; half < 2; ++half) {
      uint32_t bw = 0;
      for (int oc = 0; oc < 32; ++oc) {
        int ocg = half * 32 + oc;
        // wave-uniform weight index -> scalar (s_load) path
        int widx = __builtin_amdgcn_readfirstlane((br * 64 + ocg) * 40);
        const uint4* wp = (const uint4*)(wl1 + widx);
        int acc = 0;
#pragma unroll
        for (int tap = 0; tap < 5; ++tap) {
          uint4 wa = wp[tap * 2], wb = wp[tap * 2 + 1];
          int ta = __popc(ia[tap].x ^ wa.x) + __popc(ia[tap].y ^ wa.y) +
                   __popc(ia[tap].z ^ wa.z) + __popc(ia[tap].w ^ wa.w) +
                   __popc(ib[tap].x ^ wb.x) + __popc(ib[tap].y ^ wb.y) +
                   __popc(ib[tap].z ^ wb.z) + __popc(ib[tap].w ^ wb.w);
          acc += ta & msk[tap];
        }
        float v = (float)(basev - 2 * acc) + bcat[br * 64 + ocg];
        v = v >= 0.0f ? v : a1 * v;
        bw |= (v < 0.0f ? 1u : 0u) << oc;
      }
      bits[half] = bw;
    }
    outw[br * 2] = bits[0];
    outw[br * 2 + 1] = bits[1];
  }
  uint4* dst = (uint4*)(yb + (p << 3));
  dst[0] = make_uint4(outw[0], outw[1], outw[2], outw[3]);
  dst[1] = make_uint4(outw[4], outw[5], outw[6], outw[7]);
}

// ---------------- layer 2: 3x3 binary conv + bias + PReLU + residual ------
__global__ __launch_bounds__(256) void layer2(
    const uint32_t* __restrict__ yb, const uint32_t* __restrict__ wl2,
    const float* __restrict__ bc, const float* __restrict__ a2p,
    const float* __restrict__ x, float* __restrict__ out) {
  const float a2 = a2p[0];
  int p = blockIdx.x * 256 + threadIdx.x;
  int w = p & 127, h = (p >> 7) & 127, n = p >> 14;

  uint4 ia[9], ib[9];
  int msk[9];
  int nval = 0;
#pragma unroll
  for (int ky = 0; ky < 3; ++ky) {
#pragma unroll
    for (int kx = 0; kx < 3; ++kx) {
      int tap = ky * 3 + kx;
      int hh = h + ky - 1, ww = w + kx - 1;
      bool v = (hh >= 0) && (hh < HWD) && (ww >= 0) && (ww < HWD);
      msk[tap] = v ? -1 : 0;
      nval += v ? 1 : 0;
      int hc = min(max(hh, 0), HWD - 1), wc2 = min(max(ww, 0), HWD - 1);
      const uint4* src = (const uint4*)(yb + (((((n << 7) + hc) << 7) + wc2) << 3));
      ia[tap] = src[0];
      ib[tap] = src[1];
    }
  }
  int basev = 256 * nval;
  const float* xs = x + (n << 22) + (h << 7) + w;
  float* os = out + (n << 22) + (h << 7) + w;

  for (int ocg = 0; ocg < 256; ++ocg) {
    // wave-uniform weight index -> scalar (s_load) path
    int widx = __builtin_amdgcn_readfirstlane(ocg * 72);
    const uint4* wp = (const uint4*)(wl2 + widx);
    int acc = 0;
#pragma unroll
    for (int tap = 0; tap < 9; ++tap) {
      uint4 wa = wp[tap * 2], wb = wp[tap * 2 + 1];
      int ta = __popc(ia[tap].x ^ wa.x) + __popc(ia[tap].y ^ wa.y) +
               __popc(ia[tap].z ^ wa.z) + __popc(ia[tap].w ^ wa.w) +
               __popc(ib[tap].x ^ wb.x) + __popc(ib[tap].y ^ wb.y) +
               __popc(ib[tap].z ^ wb.z) + __popc(ib[tap].w ^ wb.w);
      acc += ta & msk[tap];
    }
    float v = (float)(basev - 2 * acc) + bc[ocg];
    v = v >= 0.0f ? v : a2 * v;
    os[ocg << 14] = v + xs[ocg << 14];
  }
}

extern "C" void kernel_launch(void* const* d_in, const int* in_sizes, int n_in,
                              void* d_out, int out_size, void* d_ws, size_t ws_size,
                              hipStream_t stream) {
  const float* x  = (const float*)d_in[0];
  const float* w1 = (const float*)d_in[1];
  const float* b1 = (const float*)d_in[2];
  const float* w2 = (const float*)d_in[3];
  const float* b2 = (const float*)d_in[4];
  const float* w3 = (const float*)d_in[5];
  const float* b3 = (const float*)d_in[6];
  const float* w4 = (const float*)d_in[7];
  const float* b4 = (const float*)d_in[8];
  const float* a1 = (const float*)d_in[9];
  const float* wc = (const float*)d_in[10];
  const float* bc = (const float*)d_in[11];
  const float* a2 = (const float*)d_in[12];
  float* out = (float*)d_out;

  uint32_t* ws  = (uint32_t*)d_ws;
  uint32_t* xb  = ws;                 // 1048576 words (4 MB)
  uint32_t* yb  = ws + (1 << 20);     // 1048576 words (4 MB)
  uint32_t* wl1 = ws + (2 << 20);     // 10240 words
  uint32_t* wl2 = wl1 + 10240;        // 18432 words
  float*    bcat = (float*)(wl2 + 18432); // 256 floats

  pack_x<<<4096, 256, 0, stream>>>(x, xb);
  pack_w<<<113, 256, 0, stream>>>(w1, w2, w3, w4, wc, b1, b2, b3, b4, wl1, wl2, bcat);
  layer1<<<512, 256, 0, stream>>>(xb, yb, wl1, bcat, a1);
  layer2<<<512, 256, 0, stream>>>(yb, wl2, bc, a2, x, out);
}

// Round 2
// 516.263 us; speedup vs baseline: 1.1332x; 1.1332x over previous
//
#include <hip/hip_runtime.h>
#include <cstdint>

// Problem geometry (fixed by setup_inputs):
//   x: (8,256,128,128) f32   -> out: same
//   Binary net: all convs are XNOR-popcount over bitpacked +/-1 tensors.
// Bit convention: bit = 1  <=>  value < 0  (i.e. binarize -> -1)
// dot over one tap = 256 - 2*popc(a ^ w); zero-padded taps masked out.
//
// R1: scalar (s_load) weight path via readfirstlane — removed LDS staging.
// R2: occupancy fix — layer1/layer2 were 512 blocks = 2 blocks/CU = 21.6%
//     occupancy, latency-exposed. Split oc/branch loops across blockIdx:
//     grid 512 -> 2048 blocks (layer2: 4 oc-chunks of 64; layer1: 4 branches).
//     Nontemporal store for `out` so the 134 MB stream doesn't evict the
//     L2-resident bitplanes that are now re-read per chunk.

#define HWD 128
#define NB  8

// ---------------- pack x -> xb (1 word per 32 channels) --------------------
__global__ __launch_bounds__(256) void pack_x(const float* __restrict__ x,
                                              uint32_t* __restrict__ xb) {
  int id = blockIdx.x * 256 + threadIdx.x;        // 0 .. 1048575
  int w  = id & 127;
  int wd = (id >> 7) & 7;
  int h  = (id >> 10) & 127;
  int n  = id >> 17;
  const float* src = x + ((n * 256 + wd * 32) << 14) + (h << 7) + w;
  uint32_t bits = 0;
#pragma unroll
  for (int i = 0; i < 32; ++i) {
    float v = src[i << 14];
    bits |= (v < 0.0f ? 1u : 0u) << i;
  }
  xb[(((((n << 7) + h) << 7) + w) << 3) + wd] = bits;
}

// ---------------- pack weights (binarized) + concat bias -------------------
// wl1: [4 branches][64 oc][5 taps][8 words]   = 10240 words
// wl2: [256 oc][9 taps][8 words]              = 18432 words
// bcat: [256] f32 (b1|b2|b3|b4)
__global__ __launch_bounds__(256) void pack_w(
    const float* __restrict__ w1, const float* __restrict__ w2,
    const float* __restrict__ w3, const float* __restrict__ w4,
    const float* __restrict__ wc,
    const float* __restrict__ b1, const float* __restrict__ b2,
    const float* __restrict__ b3, const float* __restrict__ b4,
    uint32_t* __restrict__ wl1, uint32_t* __restrict__ wl2,
    float* __restrict__ bcat) {
  int id = blockIdx.x * 256 + threadIdx.x;        // 0 .. 28927
  if (id < 10240) {
    int wd  = id & 7;
    int tap = (id >> 3) % 5;
    int oc  = (id / 40) & 63;
    int br  = id / 2560;
    const float* w = (br == 0) ? w1 : (br == 1) ? w2 : (br == 2) ? w3 : w4;
    uint32_t bits = 0;
#pragma unroll
    for (int i = 0; i < 32; ++i) {
      float v = w[(oc * 256 + wd * 32 + i) * 5 + tap];
      bits |= (v < 0.0f ? 1u : 0u) << i;
    }
    wl1[id] = bits;
  } else if (id < 28672) {
    int id2 = id - 10240;
    int wd  = id2 & 7;
    int tap = (id2 >> 3) % 9;
    int oc  = id2 / 72;
    uint32_t bits = 0;
#pragma unroll
    for (int i = 0; i < 32; ++i) {
      float v = wc[(oc * 256 + wd * 32 + i) * 9 + tap];
      bits |= (v < 0.0f ? 1u : 0u) << i;
    }
    wl2[id2] = bits;
  } else if (id < 28928) {
    int c = id - 28672;
    float v = (c < 64) ? b1[c] : (c < 128) ? b2[c - 64]
              : (c < 192) ? b3[c - 128] : b4[c - 192];
    bcat[c] = v;
  }
}

// ---------------- layer 1: 4 binary branches + bias + PReLU + binarize ----
// Grid: 2048 blocks. blockIdx>>9 selects the branch (0..3); each block
// computes 64 oc of one branch for 256 pixels and writes 2 words of yb.
__global__ __launch_bounds__(256) void layer1(
    const uint32_t* __restrict__ xb, uint32_t* __restrict__ yb,
    const uint32_t* __restrict__ wl1, const float* __restrict__ bcat,
    const float* __restrict__ a1p) {
  const float a1 = a1p[0];
  const int bid = blockIdx.x;
  const int br  = bid >> 9;                 // wave-uniform branch id
  int p = (bid & 511) * 256 + threadIdx.x;
  int w = p & 127, h = (p >> 7) & 127, n = p >> 14;

  uint4 ia[5], ib[5];
  int msk[5];
  int nval = 0;
#pragma unroll
  for (int tap = 0; tap < 5; ++tap) {
    int dh = 0, dw = 0;
    if (br == 0) dw = tap - 2;
    else if (br == 1) dw = 2 * tap - 4;
    else if (br == 2) dh = tap - 2;
    else dh = 2 * tap - 4;
    int hh = h + dh, ww = w + dw;
    bool v = (hh >= 0) && (hh < HWD) && (ww >= 0) && (ww < HWD);
    msk[tap] = v ? -1 : 0;
    nval += v ? 1 : 0;
    int hc = min(max(hh, 0), HWD - 1), wc2 = min(max(ww, 0), HWD - 1);
    const uint4* src = (const uint4*)(xb + (((((n << 7) + hc) << 7) + wc2) << 3));
    ia[tap] = src[0];
    ib[tap] = src[1];
  }
  int basev = 256 * nval;
  uint32_t bits[2];
#pragma unroll
  for (int half = 0; half < 2; ++half) {
    uint32_t bw = 0;
    for (int oc = 0; oc < 32; ++oc) {
      int ocg = half * 32 + oc;
      // wave-uniform weight index -> scalar (s_load) path
      int widx = __builtin_amdgcn_readfirstlane((br * 64 + ocg) * 40);
      const uint4* wp = (const uint4*)(wl1 + widx);
      int acc = 0;
#pragma unroll
      for (int tap = 0; tap < 5; ++tap) {
        uint4 wa = wp[tap * 2], wb = wp[tap * 2 + 1];
        int ta = __popc(ia[tap].x ^ wa.x) + __popc(ia[tap].y ^ wa.y) +
                 __popc(ia[tap].z ^ wa.z) + __popc(ia[tap].w ^ wa.w) +
                 __popc(ib[tap].x ^ wb.x) + __popc(ib[tap].y ^ wb.y) +
                 __popc(ib[tap].z ^ wb.z) + __popc(ib[tap].w ^ wb.w);
        acc += ta & msk[tap];
      }
      float v = (float)(basev - 2 * acc) + bcat[br * 64 + ocg];
      v = v >= 0.0f ? v : a1 * v;
      bw |= (v < 0.0f ? 1u : 0u) << oc;
    }
    bits[half] = bw;
  }
  uint2* dst = (uint2*)(yb + (p << 3) + br * 2);
  *dst = make_uint2(bits[0], bits[1]);
}

// ---------------- layer 2: 3x3 binary conv + bias + PReLU + residual ------
// Grid: 2048 blocks. blockIdx>>9 selects the oc-chunk (64 oc); each block
// computes 64 output channels for 256 pixels.
__global__ __launch_bounds__(256) void layer2(
    const uint32_t* __restrict__ yb, const uint32_t* __restrict__ wl2,
    const float* __restrict__ bc, const float* __restrict__ a2p,
    const float* __restrict__ x, float* __restrict__ out) {
  const float a2 = a2p[0];
  const int bid   = blockIdx.x;
  const int chunk = bid >> 9;               // wave-uniform oc chunk (0..3)
  int p = (bid & 511) * 256 + threadIdx.x;
  int w = p & 127, h = (p >> 7) & 127, n = p >> 14;

  uint4 ia[9], ib[9];
  int msk[9];
  int nval = 0;
#pragma unroll
  for (int ky = 0; ky < 3; ++ky) {
#pragma unroll
    for (int kx = 0; kx < 3; ++kx) {
      int tap = ky * 3 + kx;
      int hh = h + ky - 1, ww = w + kx - 1;
      bool v = (hh >= 0) && (hh < HWD) && (ww >= 0) && (ww < HWD);
      msk[tap] = v ? -1 : 0;
      nval += v ? 1 : 0;
      int hc = min(max(hh, 0), HWD - 1), wc2 = min(max(ww, 0), HWD - 1);
      const uint4* src = (const uint4*)(yb + (((((n << 7) + hc) << 7) + wc2) << 3));
      ia[tap] = src[0];
      ib[tap] = src[1];
    }
  }
  int basev = 256 * nval;
  const int ocbase = chunk * 64;
  const float* xs = x + (n << 22) + (ocbase << 14) + (h << 7) + w;
  float* os = out + (n << 22) + (ocbase << 14) + (h << 7) + w;

  for (int o = 0; o < 64; ++o) {
    int ocg = ocbase + o;
    // wave-uniform weight index -> scalar (s_load) path
    int widx = __builtin_amdgcn_readfirstlane(ocg * 72);
    const uint4* wp = (const uint4*)(wl2 + widx);
    int acc = 0;
#pragma unroll
    for (int tap = 0; tap < 9; ++tap) {
      uint4 wa = wp[tap * 2], wb = wp[tap * 2 + 1];
      int ta = __popc(ia[tap].x ^ wa.x) + __popc(ia[tap].y ^ wa.y) +
               __popc(ia[tap].z ^ wa.z) + __popc(ia[tap].w ^ wa.w) +
               __popc(ib[tap].x ^ wb.x) + __popc(ib[tap].y ^ wb.y) +
               __popc(ib[tap].z ^ wb.z) + __popc(ib[tap].w ^ wb.w);
      acc += ta & msk[tap];
    }
    float v = (float)(basev - 2 * acc) + bc[ocg];
    v = v >= 0.0f ? v : a2 * v;
    __builtin_nontemporal_store(v + xs[o << 14], &os[o << 14]);
  }
}

extern "C" void kernel_launch(void* const* d_in, const int* in_sizes, int n_in,
                              void* d_out, int out_size, void* d_ws, size_t ws_size,
                              hipStream_t stream) {
  const float* x  = (const float*)d_in[0];
  const float* w1 = (const float*)d_in[1];
  const float* b1 = (const float*)d_in[2];
  const float* w2 = (const float*)d_in[3];
  const float* b2 = (const float*)d_in[4];
  const float* w3 = (const float*)d_in[5];
  const float* b3 = (const float*)d_in[6];
  const float* w4 = (const float*)d_in[7];
  const float* b4 = (const float*)d_in[8];
  const float* a1 = (const float*)d_in[9];
  const float* wc = (const float*)d_in[10];
  const float* bc = (const float*)d_in[11];
  const float* a2 = (const float*)d_in[12];
  float* out = (float*)d_out;

  uint32_t* ws  = (uint32_t*)d_ws;
  uint32_t* xb  = ws;                 // 1048576 words (4 MB)
  uint32_t* yb  = ws + (1 << 20);     // 1048576 words (4 MB)
  uint32_t* wl1 = ws + (2 << 20);     // 10240 words
  uint32_t* wl2 = wl1 + 10240;        // 18432 words
  float*    bcat = (float*)(wl2 + 18432); // 256 floats

  pack_x<<<4096, 256, 0, stream>>>(x, xb);
  pack_w<<<113, 256, 0, stream>>>(w1, w2, w3, w4, wc, b1, b2, b3, b4, wl1, wl2, bcat);
  layer1<<<2048, 256, 0, stream>>>(xb, yb, wl1, bcat, a1);
  layer2<<<2048, 256, 0, stream>>>(yb, wl2, bc, a2, x, out);
}